// Round 1
// baseline (250.471 us; speedup 1.0000x reference)
//
#include <hip/hip_runtime.h>
#include <hip/hip_bf16.h>
#include <cstdint>

#define BATCH 4096
#define LAT   2048
#define NFREQ 2074
#define KPAD  2112   // NFREQ padded up to a multiple of 64 (zero-filled)

typedef __bf16 bf16x8 __attribute__((ext_vector_type(8)));
typedef float  f32x4  __attribute__((ext_vector_type(4)));

__device__ __forceinline__ unsigned short f2bf(float f) {
    // round-to-nearest-even fp32 -> bf16
    unsigned int u = __float_as_uint(f);
    u = (u + 0x7fffu + ((u >> 16) & 1u)) >> 16;
    return (unsigned short)u;
}

__device__ __forceinline__ void gload_lds16(const unsigned short* g, unsigned short* l) {
    // async global->LDS, 16 bytes per lane; LDS dest is wave-uniform base + lane*16
    __builtin_amdgcn_global_load_lds(
        (const __attribute__((address_space(1))) unsigned int*)g,
        (__attribute__((address_space(3))) unsigned int*)l,
        16, 0, 0);
}

// ---------------------------------------------------------------------------
// cast x (fp32) -> bf16, 8 elements/thread; thread 0 inits the max scalar.
__global__ void cast_x_kernel(const float* __restrict__ x,
                              unsigned short* __restrict__ xb,
                              float* __restrict__ maxp) {
    int i = blockIdx.x * blockDim.x + threadIdx.x;   // one per 8 elements
    const float4* x4 = (const float4*)x;
    float4 a = x4[2 * i];
    float4 b = x4[2 * i + 1];
    union { unsigned short us[8]; uint4 v; } p;
    p.us[0] = f2bf(a.x); p.us[1] = f2bf(a.y); p.us[2] = f2bf(a.z); p.us[3] = f2bf(a.w);
    p.us[4] = f2bf(b.x); p.us[5] = f2bf(b.y); p.us[6] = f2bf(b.z); p.us[7] = f2bf(b.w);
    ((uint4*)xb)[i] = p.v;
    if (i == 0) *maxp = -__builtin_inff();
}

// ---------------------------------------------------------------------------
// transpose + cast: in fp32 [R][C]  ->  out bf16 [C][RP], rows r>=R zero-padded.
// 64x64 tiles, 256 threads.
__global__ void transpose_cast_kernel(const float* __restrict__ in,
                                      unsigned short* __restrict__ out,
                                      int R, int C, int RP) {
    __shared__ float t[64][65];
    int r0 = blockIdx.y * 64;
    int c0 = blockIdx.x * 64;
    for (int i = threadIdx.x; i < 4096; i += 256) {
        int rr = i >> 6, cc = i & 63;
        int r = r0 + rr;
        float v = (r < R) ? in[(size_t)r * C + c0 + cc] : 0.0f;
        t[rr][cc] = v;
    }
    __syncthreads();
    for (int i = threadIdx.x; i < 4096; i += 256) {
        int cc = i >> 6, rr = i & 63;
        out[(size_t)(c0 + cc) * RP + (r0 + rr)] = f2bf(t[rr][cc]);
    }
}

// ---------------------------------------------------------------------------
// GEMM: C[m][n] = sum_k A[m][k] * Bt[n][k]
// A: bf16 row-major [M][K]; Bt: bf16 row-major [N][K]; K % 32 == 0.
// 128x128 block tile, BK=32, 4 waves in 2x2, each wave 64x64 via 4x4 MFMAs.
// BF16_OUT: store bf16 C. Else: store fp32 C and atomicMax the global max.
template <int M, int N, int K, bool BF16_OUT>
__global__ __launch_bounds__(256)
void gemm_bt_kernel(const unsigned short* __restrict__ A,
                    const unsigned short* __restrict__ Bt,
                    void* __restrict__ Cout,
                    float* __restrict__ maxp) {
    __shared__ alignas(16) unsigned short As[128 * 32];
    __shared__ alignas(16) unsigned short Bs[128 * 32];

    const int tid  = threadIdx.x;
    const int wave = tid >> 6;
    const int lane = tid & 63;
    const int wm   = (wave >> 1) * 64;
    const int wn   = (wave & 1) * 64;
    const int quad = lane >> 4;
    const int l16  = lane & 15;

    const int mBase = blockIdx.y * 128;
    const int nBase = blockIdx.x * 128;

    // staging: each wave fills two 16-row (1 KiB) chunks of As and Bs
    const int srow = lane >> 2;        // 0..15 row within chunk
    const int sk   = (lane & 3) * 8;   // 0,8,16,24 k-offset

    const unsigned short* Ab1 = A  + (size_t)(mBase + wave * 16 + srow) * K + sk;
    const unsigned short* Ab2 = A  + (size_t)(mBase + (wave + 4) * 16 + srow) * K + sk;
    const unsigned short* Bb1 = Bt + (size_t)(nBase + wave * 16 + srow) * K + sk;
    const unsigned short* Bb2 = Bt + (size_t)(nBase + (wave + 4) * 16 + srow) * K + sk;

    unsigned short* AsW1 = &As[(wave * 16) * 32];       // wave-uniform LDS chunk bases
    unsigned short* AsW2 = &As[((wave + 4) * 16) * 32];
    unsigned short* BsW1 = &Bs[(wave * 16) * 32];
    unsigned short* BsW2 = &Bs[((wave + 4) * 16) * 32];

    f32x4 acc[4][4] = {};

    for (int k0 = 0; k0 < K; k0 += 32) {
        __syncthreads();
        gload_lds16(Ab1 + k0, AsW1);
        gload_lds16(Ab2 + k0, AsW2);
        gload_lds16(Bb1 + k0, BsW1);
        gload_lds16(Bb2 + k0, BsW2);
        __syncthreads();

        bf16x8 af[4], bf[4];
#pragma unroll
        for (int mi = 0; mi < 4; ++mi)
            af[mi] = *(const bf16x8*)&As[(wm + mi * 16 + l16) * 32 + quad * 8];
#pragma unroll
        for (int ni = 0; ni < 4; ++ni)
            bf[ni] = *(const bf16x8*)&Bs[(wn + ni * 16 + l16) * 32 + quad * 8];
#pragma unroll
        for (int mi = 0; mi < 4; ++mi)
#pragma unroll
            for (int ni = 0; ni < 4; ++ni)
                acc[mi][ni] = __builtin_amdgcn_mfma_f32_16x16x32_bf16(
                    af[mi], bf[ni], acc[mi][ni], 0, 0, 0);
    }

    // epilogue: C/D layout col = lane&15, row = quad*4 + reg
    if constexpr (BF16_OUT) {
        unsigned short* C = (unsigned short*)Cout;
#pragma unroll
        for (int mi = 0; mi < 4; ++mi)
#pragma unroll
            for (int ni = 0; ni < 4; ++ni) {
                int col = nBase + wn + ni * 16 + l16;
#pragma unroll
                for (int r = 0; r < 4; ++r) {
                    int row = mBase + wm + mi * 16 + quad * 4 + r;
                    C[(size_t)row * N + col] = f2bf(acc[mi][ni][r]);
                }
            }
    } else {
        float* C = (float*)Cout;
        float vmax = -__builtin_inff();
#pragma unroll
        for (int mi = 0; mi < 4; ++mi)
#pragma unroll
            for (int ni = 0; ni < 4; ++ni) {
                int col = nBase + wn + ni * 16 + l16;
#pragma unroll
                for (int r = 0; r < 4; ++r) {
                    int row = mBase + wm + mi * 16 + quad * 4 + r;
                    float v = acc[mi][ni][r];
                    C[(size_t)row * N + col] = v;
                    vmax = fmaxf(vmax, v);
                }
            }
#pragma unroll
        for (int off = 32; off > 0; off >>= 1)
            vmax = fmaxf(vmax, __shfl_xor(vmax, off));
        if (lane == 0) {
            // signed-int / unsigned-int punning atomic float max (init = -inf)
            if (vmax >= 0.0f) atomicMax((int*)maxp, __float_as_int(vmax));
            else              atomicMin((unsigned int*)maxp, __float_as_uint(vmax));
        }
    }
}

// ---------------------------------------------------------------------------
__global__ void scale_kernel(float* __restrict__ out, const float* __restrict__ maxp) {
    int i = blockIdx.x * blockDim.x + threadIdx.x;
    float inv = 1.0f / (*maxp);
    float4* o4 = (float4*)out;
    float4 v = o4[i];
    v.x *= inv; v.y *= inv; v.z *= inv; v.w *= inv;
    o4[i] = v;
}

// ---------------------------------------------------------------------------
extern "C" void kernel_launch(void* const* d_in, const int* in_sizes, int n_in,
                              void* d_out, int out_size, void* d_ws, size_t ws_size,
                              hipStream_t stream) {
    const float* x  = (const float*)d_in[0];  // (4096, 2048)
    const float* W  = (const float*)d_in[1];  // (2074, 2048)
    const float* cb = (const float*)d_in[2];  // (2074, 2048)

    char* ws = (char*)d_ws;
    unsigned short* xb   = (unsigned short*)ws;                               // [4096][2048] bf16
    unsigned short* WT   = (unsigned short*)(ws + (size_t)BATCH * LAT * 2);   // [2048][2112] bf16
    unsigned short* cosT = (unsigned short*)((char*)WT + (size_t)LAT * KPAD * 2);
    unsigned short* C1   = (unsigned short*)((char*)cosT + (size_t)LAT * KPAD * 2); // [2048][2048] bf16
    float*          maxp = (float*)((char*)C1 + (size_t)LAT * LAT * 2);
    float*          out  = (float*)d_out;

    // 1. cast x to bf16 (+ init max scalar)
    cast_x_kernel<<<(BATCH * LAT / 8) / 256, 256, 0, stream>>>(x, xb, maxp);

    // 2./3. transpose+cast W and cos_basis to [LAT][KPAD] bf16 (zero-padded K)
    dim3 tg(LAT / 64, KPAD / 64);
    transpose_cast_kernel<<<tg, 256, 0, stream>>>(W,  WT,   NFREQ, LAT, KPAD);
    transpose_cast_kernel<<<tg, 256, 0, stream>>>(cb, cosT, NFREQ, LAT, KPAD);

    // 4. C1[l2][l1] = sum_f cosT[l2,f] * WT[l1,f]   (= (W^T @ cos)^T, GEMM2's Bt)
    gemm_bt_kernel<LAT, LAT, KPAD, true>
        <<<dim3(LAT / 128, LAT / 128), 256, 0, stream>>>(cosT, WT, (void*)C1, nullptr);

    // 5. out[b][l2] = sum_l1 xb[b][l1] * C1[l2][l1]  (fp32 out + global max)
    gemm_bt_kernel<BATCH, LAT, LAT, false>
        <<<dim3(LAT / 128, BATCH / 128), 256, 0, stream>>>(xb, C1, (void*)out, maxp);

    // 6. out /= max
    scale_kernel<<<(out_size / 4) / 256, 256, 0, stream>>>(out, maxp);
}

// Round 2
// 233.478 us; speedup vs baseline: 1.0728x; 1.0728x over previous
//
#include <hip/hip_runtime.h>
#include <hip/hip_bf16.h>
#include <cstdint>

#define BATCH 4096
#define LAT   2048
#define NFREQ 2074
#define KPAD  2112   // NFREQ padded up to a multiple of 64 (zero-filled)

typedef __bf16 bf16x8 __attribute__((ext_vector_type(8)));
typedef float  f32x4  __attribute__((ext_vector_type(4)));

__device__ __forceinline__ unsigned short f2bf(float f) {
    // round-to-nearest-even fp32 -> bf16
    unsigned int u = __float_as_uint(f);
    u = (u + 0x7fffu + ((u >> 16) & 1u)) >> 16;
    return (unsigned short)u;
}

__device__ __forceinline__ void gload_lds16(const unsigned short* g, unsigned short* l) {
    // async global->LDS, 16 bytes per lane; LDS dest is wave-uniform base + lane*16
    __builtin_amdgcn_global_load_lds(
        (const __attribute__((address_space(1))) unsigned int*)g,
        (__attribute__((address_space(3))) unsigned int*)l,
        16, 0, 0);
}

// ---------------------------------------------------------------------------
// prep: blocks [0,4096)        -> cast x fp32 -> bf16 (8 elem/thread) + init max
//       blocks [4096,5152)     -> transpose+cast W  -> WT  [LAT][KPAD]
//       blocks [5152,6208)     -> transpose+cast cb -> cosT[LAT][KPAD]
__global__ void prep_kernel(const float* __restrict__ x,
                            const float* __restrict__ W,
                            const float* __restrict__ cb,
                            unsigned short* __restrict__ xb,
                            unsigned short* __restrict__ WT,
                            unsigned short* __restrict__ cosT,
                            float* __restrict__ maxp) {
    __shared__ float t[64][65];
    const int bid = blockIdx.x;
    const int tid = threadIdx.x;
    if (bid < 4096) {
        int i = bid * 256 + tid;   // one per 8 elements
        const float4* x4 = (const float4*)x;
        float4 a = x4[2 * i];
        float4 b = x4[2 * i + 1];
        union { unsigned short us[8]; uint4 v; } p;
        p.us[0] = f2bf(a.x); p.us[1] = f2bf(a.y); p.us[2] = f2bf(a.z); p.us[3] = f2bf(a.w);
        p.us[4] = f2bf(b.x); p.us[5] = f2bf(b.y); p.us[6] = f2bf(b.z); p.us[7] = f2bf(b.w);
        ((uint4*)xb)[i] = p.v;
        if (i == 0) *maxp = -__builtin_inff();
        return;
    }
    // transpose+cast: in fp32 [R=NFREQ][C=LAT] -> out bf16 [C][KPAD], zero-padded rows
    int b2 = bid - 4096;
    const float* in        = (b2 < 1056) ? W  : cb;
    unsigned short* out    = (b2 < 1056) ? WT : cosT;
    if (b2 >= 1056) b2 -= 1056;
    const int c0 = (b2 % 32) * 64;   // column tile of input (C = LAT = 2048 -> 32 tiles)
    const int r0 = (b2 / 32) * 64;   // row tile (padded R = KPAD = 2112 -> 33 tiles)
    for (int i = tid; i < 4096; i += 256) {
        int rr = i >> 6, cc = i & 63;
        int r = r0 + rr;
        float v = (r < NFREQ) ? in[(size_t)r * LAT + c0 + cc] : 0.0f;
        t[rr][cc] = v;
    }
    __syncthreads();
    for (int i = tid; i < 4096; i += 256) {
        int cc = i >> 6, rr = i & 63;
        out[(size_t)(c0 + cc) * KPAD + (r0 + rr)] = f2bf(t[rr][cc]);
    }
}

// ---------------------------------------------------------------------------
// GEMM: C[m][n] = sum_k A[m][k] * Bt[n][k]
// A: bf16 row-major [M][K]; Bt: bf16 row-major [N][K]; K % 32 == 0.
// 128x128 block tile, BK=32, 4 waves in 2x2, each wave 64x64 via 4x4 MFMAs.
// 3-stage circular LDS pipeline: one raw s_barrier per K-iter; the 4 prefetch
// global_load_lds for tile j+1 stay in flight across the barrier (vmcnt(4)),
// overlapping DMA with the MFMAs of tile j. 3 buffers make the single-barrier
// scheme WAR-safe: buffer written at iter j was last read at iter j-2,
// separated by barrier j-1.
template <int M, int N, int K, bool BF16_OUT>
__global__ __launch_bounds__(256)
void gemm_bt_kernel(const unsigned short* __restrict__ A,
                    const unsigned short* __restrict__ Bt,
                    void* __restrict__ Cout,
                    float* __restrict__ maxp) {
    __shared__ alignas(16) unsigned short As[3][128 * 32];
    __shared__ alignas(16) unsigned short Bs[3][128 * 32];

    const int tid  = threadIdx.x;
    const int wave = tid >> 6;
    const int lane = tid & 63;
    const int wm   = (wave >> 1) * 64;
    const int wn   = (wave & 1) * 64;
    const int quad = lane >> 4;
    const int l16  = lane & 15;

    const int mBase = blockIdx.y * 128;
    const int nBase = blockIdx.x * 128;

    // staging: each wave fills two 16-row (1 KiB) chunks of As and Bs
    const int srow = lane >> 2;        // 0..15 row within chunk
    const int sk   = (lane & 3) * 8;   // 0,8,16,24 k-offset

    const unsigned short* Ab1 = A  + (size_t)(mBase + wave * 16 + srow) * K + sk;
    const unsigned short* Ab2 = A  + (size_t)(mBase + (wave + 4) * 16 + srow) * K + sk;
    const unsigned short* Bb1 = Bt + (size_t)(nBase + wave * 16 + srow) * K + sk;
    const unsigned short* Bb2 = Bt + (size_t)(nBase + (wave + 4) * 16 + srow) * K + sk;

    const int aoff1 = (wave * 16) * 32;        // wave-uniform LDS chunk offsets
    const int aoff2 = ((wave + 4) * 16) * 32;

    constexpr int NIT = K / 32;

    // prologue: issue tile 0 into buffer 0
    {
        gload_lds16(Ab1, &As[0][aoff1]);
        gload_lds16(Ab2, &As[0][aoff2]);
        gload_lds16(Bb1, &Bs[0][aoff1]);
        gload_lds16(Bb2, &Bs[0][aoff2]);
    }

    f32x4 acc[4][4] = {};

    int bc = 0;  // compute buffer for iter j
    for (int j = 0; j < NIT; ++j) {
        const int bn = (bc == 2) ? 0 : bc + 1;
        if (j + 1 < NIT) {
            const int k0 = (j + 1) * 32;
            gload_lds16(Ab1 + k0, &As[bn][aoff1]);
            gload_lds16(Ab2 + k0, &As[bn][aoff2]);
            gload_lds16(Bb1 + k0, &Bs[bn][aoff1]);
            gload_lds16(Bb2 + k0, &Bs[bn][aoff2]);
            // wait only for the 4 OLDER loads (tile j); tile j+1's 4 stay in flight
            asm volatile("s_waitcnt vmcnt(4)\n\ts_barrier" ::: "memory");
        } else {
            asm volatile("s_waitcnt vmcnt(0)\n\ts_barrier" ::: "memory");
        }

        bf16x8 af[4], bf[4];
#pragma unroll
        for (int mi = 0; mi < 4; ++mi)
            af[mi] = *(const bf16x8*)&As[bc][(wm + mi * 16 + l16) * 32 + quad * 8];
#pragma unroll
        for (int ni = 0; ni < 4; ++ni)
            bf[ni] = *(const bf16x8*)&Bs[bc][(wn + ni * 16 + l16) * 32 + quad * 8];
#pragma unroll
        for (int mi = 0; mi < 4; ++mi)
#pragma unroll
            for (int ni = 0; ni < 4; ++ni)
                acc[mi][ni] = __builtin_amdgcn_mfma_f32_16x16x32_bf16(
                    af[mi], bf[ni], acc[mi][ni], 0, 0, 0);
        bc = bn;
    }

    // epilogue: C/D layout col = lane&15, row = quad*4 + reg
    if constexpr (BF16_OUT) {
        unsigned short* C = (unsigned short*)Cout;
#pragma unroll
        for (int mi = 0; mi < 4; ++mi)
#pragma unroll
            for (int ni = 0; ni < 4; ++ni) {
                int col = nBase + wn + ni * 16 + l16;
#pragma unroll
                for (int r = 0; r < 4; ++r) {
                    int row = mBase + wm + mi * 16 + quad * 4 + r;
                    C[(size_t)row * N + col] = f2bf(acc[mi][ni][r]);
                }
            }
    } else {
        float* C = (float*)Cout;
        float vmax = -__builtin_inff();
#pragma unroll
        for (int mi = 0; mi < 4; ++mi)
#pragma unroll
            for (int ni = 0; ni < 4; ++ni) {
                int col = nBase + wn + ni * 16 + l16;
#pragma unroll
                for (int r = 0; r < 4; ++r) {
                    int row = mBase + wm + mi * 16 + quad * 4 + r;
                    float v = acc[mi][ni][r];
                    C[(size_t)row * N + col] = v;
                    vmax = fmaxf(vmax, v);
                }
            }
#pragma unroll
        for (int off = 32; off > 0; off >>= 1)
            vmax = fmaxf(vmax, __shfl_xor(vmax, off));
        if (lane == 0) {
            // signed-int / unsigned-int punning atomic float max (init = -inf)
            if (vmax >= 0.0f) atomicMax((int*)maxp, __float_as_int(vmax));
            else              atomicMin((unsigned int*)maxp, __float_as_uint(vmax));
        }
    }
}

// ---------------------------------------------------------------------------
__global__ void scale_kernel(float* __restrict__ out, const float* __restrict__ maxp) {
    int i = blockIdx.x * blockDim.x + threadIdx.x;
    float inv = 1.0f / (*maxp);
    float4* o4 = (float4*)out;
    float4 v = o4[i];
    v.x *= inv; v.y *= inv; v.z *= inv; v.w *= inv;
    o4[i] = v;
}

// ---------------------------------------------------------------------------
extern "C" void kernel_launch(void* const* d_in, const int* in_sizes, int n_in,
                              void* d_out, int out_size, void* d_ws, size_t ws_size,
                              hipStream_t stream) {
    const float* x  = (const float*)d_in[0];  // (4096, 2048)
    const float* W  = (const float*)d_in[1];  // (2074, 2048)
    const float* cb = (const float*)d_in[2];  // (2074, 2048)

    char* ws = (char*)d_ws;
    unsigned short* xb   = (unsigned short*)ws;                               // [4096][2048] bf16
    unsigned short* WT   = (unsigned short*)(ws + (size_t)BATCH * LAT * 2);   // [2048][2112] bf16
    unsigned short* cosT = (unsigned short*)((char*)WT + (size_t)LAT * KPAD * 2);
    unsigned short* C1   = (unsigned short*)((char*)cosT + (size_t)LAT * KPAD * 2); // [2048][2048] bf16
    float*          maxp = (float*)((char*)C1 + (size_t)LAT * LAT * 2);
    float*          out  = (float*)d_out;

    // 1. fused prep: cast x -> bf16 (+init max), transpose+cast W and cos_basis
    prep_kernel<<<4096 + 2 * 1056, 256, 0, stream>>>(x, W, cb, xb, WT, cosT, maxp);

    // 2. C1[l2][l1] = sum_f cosT[l2,f] * WT[l1,f]   (= (W^T @ cos)^T, GEMM2's Bt)
    gemm_bt_kernel<LAT, LAT, KPAD, true>
        <<<dim3(LAT / 128, LAT / 128), 256, 0, stream>>>(cosT, WT, (void*)C1, nullptr);

    // 3. out[b][l2] = sum_l1 xb[b][l1] * C1[l2][l1]  (fp32 out + global max)
    gemm_bt_kernel<BATCH, LAT, LAT, false>
        <<<dim3(LAT / 128, BATCH / 128), 256, 0, stream>>>(xb, C1, (void*)out, maxp);

    // 4. out /= max
    scale_kernel<<<(out_size / 4) / 256, 256, 0, stream>>>(out, maxp);
}